// Round 10
// baseline (372.337 us; speedup 1.0000x reference)
//
#include <hip/hip_runtime.h>
#include <stdint.h>

#define Sq   2176
#define Dm   3072
#define NDm  9216
#define NH   24
#define HDm  128
#define BLKR 1152   // S - COND
#define KVH  1088   // KV half-range per split
#define NT2  34     // 32-key tiles per split

typedef __attribute__((ext_vector_type(8))) __bf16 bf16x8;
typedef __attribute__((ext_vector_type(4))) float f32x4;
typedef __attribute__((ext_vector_type(8))) unsigned short ushort8;

#define AS1 __attribute__((address_space(1)))
#define AS3 __attribute__((address_space(3)))

__device__ __forceinline__ unsigned short f2bf(float x) {
  unsigned u = __builtin_bit_cast(unsigned, x);
  u += 0x7FFFu + ((u >> 16) & 1u);   // RNE; inputs are finite randoms
  return (unsigned short)(u >> 16);
}

// ---------------- f32 -> bf16 conversion, 8 elems/thread ----------------
__global__ void cvt_kernel(const float* __restrict__ src,
                           unsigned short* __restrict__ dst, int n8) {
  int i = blockIdx.x * blockDim.x + threadIdx.x;
  if (i >= n8) return;
  const float4* s4 = (const float4*)src + (size_t)i * 2;
  float4 a = s4[0], b = s4[1];
  ushort8 o;
  o[0]=f2bf(a.x); o[1]=f2bf(a.y); o[2]=f2bf(a.z); o[3]=f2bf(a.w);
  o[4]=f2bf(b.x); o[5]=f2bf(b.y); o[6]=f2bf(b.z); o[7]=f2bf(b.w);
  *((ushort8*)dst + i) = o;
}

// 3 weight matrices in one launch (blockIdx.y selects source)
__global__ void cvt3_kernel(const float* __restrict__ w0, const float* __restrict__ w1,
                            const float* __restrict__ w2,
                            unsigned short* __restrict__ dst, int n8) {
  int i = blockIdx.x * blockDim.x + threadIdx.x;
  if (i >= n8) return;
  const float* src = blockIdx.y == 0 ? w0 : (blockIdx.y == 1 ? w1 : w2);
  const float4* s4 = (const float4*)src + (size_t)i * 2;
  float4 a = s4[0], b = s4[1];
  ushort8 o;
  o[0]=f2bf(a.x); o[1]=f2bf(a.y); o[2]=f2bf(a.z); o[3]=f2bf(a.w);
  o[4]=f2bf(b.x); o[5]=f2bf(b.y); o[6]=f2bf(b.z); o[7]=f2bf(b.w);
  *((ushort8*)dst + (size_t)blockIdx.y * (Dm * (size_t)Dm / 8) + i) = o;
}

// ---------------- fused QKV GEMM (round-8 proven: 770 TF) ----------------
__global__ __launch_bounds__(256, 4) void gemm_kernel(
    const unsigned short* __restrict__ A,
    const unsigned short* __restrict__ B,
    const float* __restrict__ bq, const float* __restrict__ bk,
    const float* __restrict__ bv, float* __restrict__ C) {
  __shared__ __attribute__((aligned(16))) unsigned short aL[128 * 64];
  __shared__ __attribute__((aligned(16))) unsigned short bL[128 * 64];
  int t = threadIdx.x;
  int wid = t >> 6, lane = t & 63;
  int lr = lane & 15, lg = lane >> 4;
  int wr = wid >> 1, wc = wid & 1;

  int bid = blockIdx.x;
  int wg = (bid & 7) * 129 + (bid >> 3);
  int mt, nt;
  if (wg < 216) { nt = wg / 9; mt = wg % 9; }
  else { int r2 = wg - 216; nt = 24 + r2 / 17; mt = r2 % 17; }
  int m0 = mt * 128, n0 = nt * 128;

  f32x4 acc[4][4];
#pragma unroll
  for (int m = 0; m < 4; m++)
#pragma unroll
    for (int n = 0; n < 4; n++) acc[m][n] = (f32x4){0.f, 0.f, 0.f, 0.f};

  int tr = t >> 3;
  int uu = (t & 7) ^ (tr & 7);
  const unsigned short* pA = A + (size_t)(m0 + tr) * Dm + uu * 8;
  const unsigned short* pB = B + (size_t)(n0 + tr) * Dm + uu * 8;

  int lr7 = lr & 7;
  int baseA = (wr * 64 + lr) * 64;
  int baseB = (wc * 64 + lr) * 64;
  int d0 = (lg ^ lr7) * 8;
  int d1 = ((4 + lg) ^ lr7) * 8;

  for (int kt = 0; kt < Dm / 64; kt++) {
    const int ko = kt * 64;
#pragma unroll
    for (int c = 0; c < 4; c++) {
      __builtin_amdgcn_global_load_lds(
          (const AS1 void*)(pA + (size_t)c * 32 * Dm + ko),
          (AS3 void*)(&aL[c * 2048 + wid * 512]), 16, 0, 0);
      __builtin_amdgcn_global_load_lds(
          (const AS1 void*)(pB + (size_t)c * 32 * Dm + ko),
          (AS3 void*)(&bL[c * 2048 + wid * 512]), 16, 0, 0);
    }
    __syncthreads();

    bf16x8 a0[4], b0[4];
#pragma unroll
    for (int m = 0; m < 4; m++) a0[m] = *(const bf16x8*)&aL[baseA + m * 1024 + d0];
#pragma unroll
    for (int n = 0; n < 4; n++) b0[n] = *(const bf16x8*)&bL[baseB + n * 1024 + d0];
#pragma unroll
    for (int m = 0; m < 4; m++)
#pragma unroll
      for (int n = 0; n < 4; n++)
        acc[m][n] = __builtin_amdgcn_mfma_f32_16x16x32_bf16(a0[m], b0[n], acc[m][n], 0, 0, 0);

    bf16x8 a1[4], b1[4];
#pragma unroll
    for (int m = 0; m < 4; m++) a1[m] = *(const bf16x8*)&aL[baseA + m * 1024 + d1];
#pragma unroll
    for (int n = 0; n < 4; n++) b1[n] = *(const bf16x8*)&bL[baseB + n * 1024 + d1];
#pragma unroll
    for (int m = 0; m < 4; m++)
#pragma unroll
      for (int n = 0; n < 4; n++)
        acc[m][n] = __builtin_amdgcn_mfma_f32_16x16x32_bf16(a1[m], b1[n], acc[m][n], 0, 0, 0);
    __syncthreads();
  }

#pragma unroll
  for (int m = 0; m < 4; m++)
#pragma unroll
    for (int n = 0; n < 4; n++) {
      int col = n0 + wc * 64 + n * 16 + lr;
      float bias = col < 3072 ? bq[col] : (col < 6144 ? bk[col - 3072] : bv[col - 6144]);
#pragma unroll
      for (int i = 0; i < 4; i++) {
        int r = m0 + wr * 64 + m * 16 + lg * 4 + i;
        C[(size_t)r * NDm + col] = acc[m][n][i] + bias;
      }
    }
}

// ---------------- LoRA for k,v only (q LoRA only touches discarded rows) ---
__global__ __launch_bounds__(256) void lora_kernel(
    const float* __restrict__ hs,
    const float* __restrict__ k_down, const float* __restrict__ k_up,
    const float* __restrict__ v_down, const float* __restrict__ v_up,
    float* __restrict__ qkv) {
  int srow = BLKR + blockIdx.x;
  int t = threadIdx.x;
  __shared__ float hsl[Dm];
  __shared__ float tl[32];
  for (int e = t; e < Dm; e += 256) hsl[e] = hs[(size_t)srow * Dm + e];
  __syncthreads();
  int dot = t >> 3, part = t & 7;
  int mat = dot >> 4, j = dot & 15;
  const float* down = mat ? v_down : k_down;
  float p = 0.f;
  for (int e = part; e < Dm; e += 8) p += hsl[e] * down[j * Dm + e];
  p += __shfl_xor(p, 1, 64);
  p += __shfl_xor(p, 2, 64);
  p += __shfl_xor(p, 4, 64);
  if (part == 0) tl[dot] = p;
  __syncthreads();
  float tk[16], tv[16];
#pragma unroll
  for (int jj = 0; jj < 16; jj++) { tk[jj] = tl[jj]; tv[jj] = tl[16 + jj]; }
  for (int n = t; n < Dm; n += 256) {
    float ak = 0.f, av = 0.f;
#pragma unroll
    for (int jj = 0; jj < 16; jj++) {
      ak += tk[jj] * k_up[n * 16 + jj];
      av += tv[jj] * v_up[n * 16 + jj];
    }
    qkv[(size_t)srow * NDm + 3072 + n] += ak;
    qkv[(size_t)srow * NDm + 6144 + n] += av;
  }
}

// ---------------- RMSNorm + RoPE -> bf16 head-major q,k ----------------
__global__ __launch_bounds__(256) void prep_kernel(
    const float* __restrict__ qkv,
    const float* __restrict__ nqw, const float* __restrict__ nkw,
    const float* __restrict__ rc, const float* __restrict__ rs,
    unsigned short* __restrict__ qh, unsigned short* __restrict__ kh) {
  int s = blockIdx.x;
  int w = threadIdx.x >> 6, l = threadIdx.x & 63;
  int d0 = l * 2;
  float c0 = rc[s * 128 + d0], c1 = rc[s * 128 + d0 + 1];
  float s0 = rs[s * 128 + d0], s1 = rs[s * 128 + d0 + 1];
  float wk0 = nkw[d0], wk1 = nkw[d0 + 1];
  float wq0 = nqw[d0], wq1 = nqw[d0 + 1];
  bool doq = (s < BLKR);

#pragma unroll
  for (int hh = 0; hh < 6; hh++) {
    int h = w * 6 + hh;
    { // k: all rows
      const float* kp = qkv + (size_t)s * NDm + 3072 + h * 128;
      float2 x = *(const float2*)(kp + d0);
      float ss = x.x * x.x + x.y * x.y;
#pragma unroll
      for (int m = 1; m < 64; m <<= 1) ss += __shfl_xor(ss, m, 64);
      float r = rsqrtf(ss * (1.f / 128.f) + 1e-6f);
      float xn0 = x.x * r * wk0, xn1 = x.y * r * wk1;
      ushort2 o = make_ushort2(f2bf(xn0 * c0 - xn1 * s0), f2bf(xn1 * c1 + xn0 * s1));
      *(ushort2*)&kh[((size_t)h * Sq + s) * 128 + d0] = o;
    }
    if (doq) { // q: only output rows
      const float* qp = qkv + (size_t)s * NDm + h * 128;
      float2 x = *(const float2*)(qp + d0);
      float ss = x.x * x.x + x.y * x.y;
#pragma unroll
      for (int m = 1; m < 64; m <<= 1) ss += __shfl_xor(ss, m, 64);
      float r = rsqrtf(ss * (1.f / 128.f) + 1e-6f);
      float xn0 = x.x * r * wq0, xn1 = x.y * r * wq1;
      ushort2 o = make_ushort2(f2bf(xn0 * c0 - xn1 * s0), f2bf(xn1 * c1 + xn0 * s1));
      *(ushort2*)&qh[((size_t)h * BLKR + s) * 128 + d0] = o;
    }
  }
}

// ---------------- v transpose to V^T per head (bf16) ----------------
__global__ __launch_bounds__(256) void vt_kernel(const float* __restrict__ qkv,
                                                 unsigned short* __restrict__ vt) {
  int st = blockIdx.x, dt = blockIdx.y, h = blockIdx.z;
  int tx = threadIdx.x & 31, ty = threadIdx.x >> 5;
  __shared__ float ld[32][33];
  int s0 = st * 32, d0 = dt * 32;
#pragma unroll
  for (int p = 0; p < 4; p++) {
    int ss = ty + p * 8;
    ld[ss][tx] = qkv[(size_t)(s0 + ss) * NDm + 6144 + h * 128 + d0 + tx];
  }
  __syncthreads();
#pragma unroll
  for (int p = 0; p < 4; p++) {
    int dd = ty + p * 8;
    vt[((size_t)h * 128 + d0 + dd) * Sq + s0 + tx] = f2bf(ld[tx][dd]);
  }
}

// ---------------- flash attention: 32-key tiles, 4 blocks/CU ---------------
// Fixed-M softmax (bounded scores), split-KV x2, LDS = 37.9 KB:
// kLds 2x8KB + vLds 2x8KB + pl 5KB -> 4 blocks/CU (was 2 at 64-key tiles).
__global__ __launch_bounds__(256) void attn_kernel(
    const unsigned short* __restrict__ qh,  // [NH][1152][128]
    const unsigned short* __restrict__ kh,  // [NH][2176][128]
    const unsigned short* __restrict__ vt,  // [NH][128][2176]
    float* __restrict__ accW,               // [2][1152][3072] partial acc
    float* __restrict__ lW) {               // [2][24][1152] partial lsum
  int bid = blockIdx.x;
  int wg = (bid & 7) * 108 + (bid >> 3);    // bijective: 864 = 8 x 108
  int h = wg / 36, rem = wg % 36;
  int qt = rem >> 1, split = rem & 1;
  int q0 = qt * 64;
  int k0 = split * KVH;

  int t = threadIdx.x;
  int w = t >> 6, lane = t & 63;
  int lr = lane & 15, lg = lane >> 4;

  __shared__ __attribute__((aligned(16))) unsigned short kLds[2][32 * 128];
  __shared__ __attribute__((aligned(16))) unsigned short vLds[2][128 * 32];
  __shared__ __attribute__((aligned(16))) unsigned short pl[4][16][40];

  const unsigned short* qb = qh + ((size_t)h * BLKR + q0 + w * 16) * 128;
  bf16x8 aq[4];
#pragma unroll
  for (int m = 0; m < 4; m++)
    aq[m] = *(const bf16x8*)(qb + (size_t)lr * 128 + m * 32 + lg * 8);

  const unsigned short* kh_h = kh + ((size_t)h * Sq + k0) * 128;
  const unsigned short* vt_h = vt + (size_t)h * 128 * Sq + k0;

  // staging sources (pre-swizzled): K tile 32x128 (16 units/row, slot^row&7);
  // V^T tile 128x32 (4 units/row, slot^row&3). Linear LDS dest = unit*16B.
  const unsigned short* srcK[2];
  const unsigned short* srcV[2];
  int kDst[2], vDst[2];
#pragma unroll
  for (int c = 0; c < 2; c++) {
    int u = c * 256 + t;
    int rK = u >> 4, sK = u & 15;
    srcK[c] = kh_h + (size_t)rK * 128 + ((sK ^ (rK & 7)) * 8);
    kDst[c] = u * 8;
    int rV = u >> 2, sV = u & 3;
    srcV[c] = vt_h + (size_t)rV * Sq + ((sV ^ (rV & 3)) * 8);
    vDst[c] = u * 8;
  }

  auto stage = [&](int kt, int buf) {
#pragma unroll
    for (int c = 0; c < 2; c++)
      __builtin_amdgcn_global_load_lds(
          (const AS1 void*)(srcK[c] + (size_t)kt * 4096),
          (AS3 void*)(&kLds[buf][kDst[c]]), 16, 0, 0);
#pragma unroll
    for (int c = 0; c < 2; c++)
      __builtin_amdgcn_global_load_lds(
          (const AS1 void*)(srcV[c] + (size_t)kt * 32),
          (AS3 void*)(&vLds[buf][vDst[c]]), 16, 0, 0);
  };

  f32x4 acc[8];
#pragma unroll
  for (int o = 0; o < 8; o++) acc[o] = (f32x4){0.f, 0.f, 0.f, 0.f};
  float lsum[4] = {0.f, 0.f, 0.f, 0.f};
  const float sc = 0.08838834764831845f;   // 1/sqrt(128)
  const float L2E = 1.4426950408889634f;
  const float ea = sc * L2E, eb = -10.0f * L2E;   // fixed M = 10

  int lr7 = lr & 7, lr3 = lr & 3;

  auto compute = [&](int buf) {
    const unsigned short* kbuf = kLds[buf];
    const unsigned short* vbuf = vLds[buf];
    f32x4 s2[2];
    s2[0] = (f32x4){0.f, 0.f, 0.f, 0.f};
    s2[1] = (f32x4){0.f, 0.f, 0.f, 0.f};
    __builtin_amdgcn_s_setprio(1);
#pragma unroll
    for (int tt = 0; tt < 2; tt++)
#pragma unroll
      for (int m = 0; m < 4; m++) {
        bf16x8 kf = *(const bf16x8*)&kbuf[(tt * 16 + lr) * 128 + ((m * 4 + lg) ^ lr7) * 8];
        s2[tt] = __builtin_amdgcn_mfma_f32_16x16x32_bf16(aq[m], kf, s2[tt], 0, 0, 0);
      }
    __builtin_amdgcn_s_setprio(0);
#pragma unroll
    for (int tt = 0; tt < 2; tt++)
#pragma unroll
      for (int i = 0; i < 4; i++) {
        float p = exp2f(fmaf(s2[tt][i], ea, eb));
        lsum[i] += p;
        pl[w][lg * 4 + i][tt * 16 + lr] = f2bf(p);
      }
    bf16x8 ap = *(const bf16x8*)&pl[w][lr][lg * 8];
    __builtin_amdgcn_s_setprio(1);
#pragma unroll
    for (int o = 0; o < 8; o++) {
      bf16x8 vf = *(const bf16x8*)&vbuf[(o * 16 + lr) * 32 + (lg ^ lr3) * 8];
      acc[o] = __builtin_amdgcn_mfma_f32_16x16x32_bf16(ap, vf, acc[o], 0, 0, 0);
    }
    __builtin_amdgcn_s_setprio(0);
  };

  stage(0, 0);
  __syncthreads();
  for (int kt = 0; kt < NT2; kt += 2) {
    stage(kt + 1, 1);
    compute(0);
    __syncthreads();
    if (kt + 2 < NT2) stage(kt + 2, 0);
    compute(1);
    __syncthreads();
  }

  // per-row lsum reduce over the 16 lr lanes
#pragma unroll
  for (int i = 0; i < 4; i++) {
#pragma unroll
    for (int d = 1; d < 16; d <<= 1) lsum[i] += __shfl_xor(lsum[i], d, 64);
  }
  float* accP = accW + (size_t)split * BLKR * 3072;
#pragma unroll
  for (int o = 0; o < 8; o++) {
    int col = h * 128 + o * 16 + lr;
#pragma unroll
    for (int i = 0; i < 4; i++) {
      int r = q0 + w * 16 + lg * 4 + i;
      accP[(size_t)r * 3072 + col] = acc[o][i];
    }
  }
  if (lr == 0) {
    float* lP = lW + (size_t)split * NH * BLKR + (size_t)h * BLKR;
#pragma unroll
    for (int i = 0; i < 4; i++) lP[q0 + w * 16 + lg * 4 + i] = lsum[i];
  }
}

// ---------------- combine: out = (a0+a1)/(l0+l1) ----------------
__global__ __launch_bounds__(256) void normalize_kernel(
    const float* __restrict__ accW, const float* __restrict__ lW,
    float* __restrict__ out) {
  int idx = blockIdx.x * 256 + threadIdx.x;      // 442368 total
  int r = idx / 384, rem = idx % 384;
  int c = rem * 8, h = c >> 7;
  const float4* a0 = (const float4*)(accW + (size_t)r * 3072 + c);
  const float4* a1 = (const float4*)(accW + (size_t)BLKR * 3072 + (size_t)r * 3072 + c);
  float l = lW[(size_t)h * BLKR + r] + lW[(size_t)NH * BLKR + (size_t)h * BLKR + r];
  float inv = 1.0f / l;
  float4 v0 = a0[0], v1 = a0[1], u0 = a1[0], u1 = a1[1];
  float4 o0, o1;
  o0.x = (v0.x + u0.x) * inv; o0.y = (v0.y + u0.y) * inv;
  o0.z = (v0.z + u0.z) * inv; o0.w = (v0.w + u0.w) * inv;
  o1.x = (v1.x + u1.x) * inv; o1.y = (v1.y + u1.y) * inv;
  o1.z = (v1.z + u1.z) * inv; o1.w = (v1.w + u1.w) * inv;
  float4* op = (float4*)(out + (size_t)r * 3072 + c);
  op[0] = o0; op[1] = o1;
}

extern "C" void kernel_launch(void* const* d_in, const int* in_sizes, int n_in,
                              void* d_out, int out_size, void* d_ws, size_t ws_size,
                              hipStream_t stream) {
  const float* hs  = (const float*)d_in[0];
  const float* Wq  = (const float*)d_in[1];
  const float* bq  = (const float*)d_in[2];
  const float* Wk  = (const float*)d_in[3];
  const float* bk  = (const float*)d_in[4];
  const float* Wv  = (const float*)d_in[5];
  const float* bv  = (const float*)d_in[6];
  const float* k_down = (const float*)d_in[9];
  const float* k_up   = (const float*)d_in[10];
  const float* v_down = (const float*)d_in[11];
  const float* v_up   = (const float*)d_in[12];
  const float* nqw = (const float*)d_in[13];
  const float* nkw = (const float*)d_in[14];
  const float* rc  = (const float*)d_in[15];
  const float* rsn = (const float*)d_in[16];
  float* out = (float*)d_out;

  char* ws = (char*)d_ws;
  unsigned short* hsb = (unsigned short*)(ws + 0);          // 13,369,344 B
  unsigned short* wb  = (unsigned short*)(ws + 13369344);   // 56,623,104 B
  float*          qkv = (float*)(ws + 69992448);            // 80,216,064 B
  unsigned short* qh  = (unsigned short*)(ws + 150208512);  //  7,077,888 B
  unsigned short* kh  = (unsigned short*)(ws + 157286400);  // 13,369,344 B
  unsigned short* vtb = (unsigned short*)(ws + 170655744);  // 13,369,344 B
  // attn partials reuse the qkv region (dead after prep+vt):
  float* accW = qkv;                                        // 28,311,552 B
  float* lW   = (float*)(ws + 69992448 + 28311552);         //    221,184 B

  const int n8_hs = Sq * Dm / 8;
  const int n8_w  = Dm * Dm / 8;
  cvt_kernel<<<dim3((n8_hs + 255) / 256), 256, 0, stream>>>(hs, hsb, n8_hs);
  cvt3_kernel<<<dim3((n8_w + 255) / 256, 3), 256, 0, stream>>>(Wq, Wk, Wv, wb, n8_w);

  gemm_kernel<<<dim3(1032), 256, 0, stream>>>(hsb, wb, bq, bk, bv, qkv);
  lora_kernel<<<dim3(Sq - BLKR), 256, 0, stream>>>(hs, k_down, k_up, v_down, v_up, qkv);
  prep_kernel<<<dim3(Sq), 256, 0, stream>>>(qkv, nqw, nkw, rc, rsn, qh, kh);
  vt_kernel<<<dim3(Sq / 32, HDm / 32, NH), 256, 0, stream>>>(qkv, vtb);
  attn_kernel<<<dim3(2 * 18 * NH), 256, 0, stream>>>(qh, kh, vtb, accW, lW);
  normalize_kernel<<<dim3(BLKR * 3072 / 8 / 256), 256, 0, stream>>>(accW, lW, out);
}

// Round 12
// 363.136 us; speedup vs baseline: 1.0253x; 1.0253x over previous
//
#include <hip/hip_runtime.h>
#include <stdint.h>

#define Sq   2176
#define Dm   3072
#define NDm  9216
#define NH   24
#define HDm  128
#define BLKR 1152   // S - COND
#define KVH  1088   // KV half-range per split
#define NT2  34     // 32-key tiles per split

typedef __attribute__((ext_vector_type(8))) __bf16 bf16x8;
typedef __attribute__((ext_vector_type(4))) float f32x4;
typedef __attribute__((ext_vector_type(8))) unsigned short ushort8;

#define AS1 __attribute__((address_space(1)))
#define AS3 __attribute__((address_space(3)))

__device__ __forceinline__ unsigned short f2bf(float x) {
  unsigned u = __builtin_bit_cast(unsigned, x);
  u += 0x7FFFu + ((u >> 16) & 1u);   // RNE; inputs are finite randoms
  return (unsigned short)(u >> 16);
}

// ---------------- f32 -> bf16 conversion, 8 elems/thread ----------------
__global__ void cvt_kernel(const float* __restrict__ src,
                           unsigned short* __restrict__ dst, int n8) {
  int i = blockIdx.x * blockDim.x + threadIdx.x;
  if (i >= n8) return;
  const float4* s4 = (const float4*)src + (size_t)i * 2;
  float4 a = s4[0], b = s4[1];
  ushort8 o;
  o[0]=f2bf(a.x); o[1]=f2bf(a.y); o[2]=f2bf(a.z); o[3]=f2bf(a.w);
  o[4]=f2bf(b.x); o[5]=f2bf(b.y); o[6]=f2bf(b.z); o[7]=f2bf(b.w);
  *((ushort8*)dst + i) = o;
}

// 3 weight matrices in one launch (blockIdx.y selects source)
__global__ void cvt3_kernel(const float* __restrict__ w0, const float* __restrict__ w1,
                            const float* __restrict__ w2,
                            unsigned short* __restrict__ dst, int n8) {
  int i = blockIdx.x * blockDim.x + threadIdx.x;
  if (i >= n8) return;
  const float* src = blockIdx.y == 0 ? w0 : (blockIdx.y == 1 ? w1 : w2);
  const float4* s4 = (const float4*)src + (size_t)i * 2;
  float4 a = s4[0], b = s4[1];
  ushort8 o;
  o[0]=f2bf(a.x); o[1]=f2bf(a.y); o[2]=f2bf(a.z); o[3]=f2bf(a.w);
  o[4]=f2bf(b.x); o[5]=f2bf(b.y); o[6]=f2bf(b.z); o[7]=f2bf(b.w);
  *((ushort8*)dst + (size_t)blockIdx.y * (Dm * (size_t)Dm / 8) + i) = o;
}

// ---------------- fused QKV GEMM (round-8 proven: 770 TF) ----------------
__global__ __launch_bounds__(256, 4) void gemm_kernel(
    const unsigned short* __restrict__ A,
    const unsigned short* __restrict__ B,
    const float* __restrict__ bq, const float* __restrict__ bk,
    const float* __restrict__ bv, float* __restrict__ C) {
  __shared__ __attribute__((aligned(16))) unsigned short aL[128 * 64];
  __shared__ __attribute__((aligned(16))) unsigned short bL[128 * 64];
  int t = threadIdx.x;
  int wid = t >> 6, lane = t & 63;
  int lr = lane & 15, lg = lane >> 4;
  int wr = wid >> 1, wc = wid & 1;

  int bid = blockIdx.x;
  int wg = (bid & 7) * 129 + (bid >> 3);
  int mt, nt;
  if (wg < 216) { nt = wg / 9; mt = wg % 9; }
  else { int r2 = wg - 216; nt = 24 + r2 / 17; mt = r2 % 17; }
  int m0 = mt * 128, n0 = nt * 128;

  f32x4 acc[4][4];
#pragma unroll
  for (int m = 0; m < 4; m++)
#pragma unroll
    for (int n = 0; n < 4; n++) acc[m][n] = (f32x4){0.f, 0.f, 0.f, 0.f};

  int tr = t >> 3;
  int uu = (t & 7) ^ (tr & 7);
  const unsigned short* pA = A + (size_t)(m0 + tr) * Dm + uu * 8;
  const unsigned short* pB = B + (size_t)(n0 + tr) * Dm + uu * 8;

  int lr7 = lr & 7;
  int baseA = (wr * 64 + lr) * 64;
  int baseB = (wc * 64 + lr) * 64;
  int d0 = (lg ^ lr7) * 8;
  int d1 = ((4 + lg) ^ lr7) * 8;

  for (int kt = 0; kt < Dm / 64; kt++) {
    const int ko = kt * 64;
#pragma unroll
    for (int c = 0; c < 4; c++) {
      __builtin_amdgcn_global_load_lds(
          (const AS1 void*)(pA + (size_t)c * 32 * Dm + ko),
          (AS3 void*)(&aL[c * 2048 + wid * 512]), 16, 0, 0);
      __builtin_amdgcn_global_load_lds(
          (const AS1 void*)(pB + (size_t)c * 32 * Dm + ko),
          (AS3 void*)(&bL[c * 2048 + wid * 512]), 16, 0, 0);
    }
    __syncthreads();

    bf16x8 a0[4], b0[4];
#pragma unroll
    for (int m = 0; m < 4; m++) a0[m] = *(const bf16x8*)&aL[baseA + m * 1024 + d0];
#pragma unroll
    for (int n = 0; n < 4; n++) b0[n] = *(const bf16x8*)&bL[baseB + n * 1024 + d0];
#pragma unroll
    for (int m = 0; m < 4; m++)
#pragma unroll
      for (int n = 0; n < 4; n++)
        acc[m][n] = __builtin_amdgcn_mfma_f32_16x16x32_bf16(a0[m], b0[n], acc[m][n], 0, 0, 0);

    bf16x8 a1[4], b1[4];
#pragma unroll
    for (int m = 0; m < 4; m++) a1[m] = *(const bf16x8*)&aL[baseA + m * 1024 + d1];
#pragma unroll
    for (int n = 0; n < 4; n++) b1[n] = *(const bf16x8*)&bL[baseB + n * 1024 + d1];
#pragma unroll
    for (int m = 0; m < 4; m++)
#pragma unroll
      for (int n = 0; n < 4; n++)
        acc[m][n] = __builtin_amdgcn_mfma_f32_16x16x32_bf16(a1[m], b1[n], acc[m][n], 0, 0, 0);
    __syncthreads();
  }

#pragma unroll
  for (int m = 0; m < 4; m++)
#pragma unroll
    for (int n = 0; n < 4; n++) {
      int col = n0 + wc * 64 + n * 16 + lr;
      float bias = col < 3072 ? bq[col] : (col < 6144 ? bk[col - 3072] : bv[col - 6144]);
#pragma unroll
      for (int i = 0; i < 4; i++) {
        int r = m0 + wr * 64 + m * 16 + lg * 4 + i;
        C[(size_t)r * NDm + col] = acc[m][n][i] + bias;
      }
    }
}

// ---------------- LoRA for k,v only (q LoRA only touches discarded rows) ---
__global__ __launch_bounds__(256) void lora_kernel(
    const float* __restrict__ hs,
    const float* __restrict__ k_down, const float* __restrict__ k_up,
    const float* __restrict__ v_down, const float* __restrict__ v_up,
    float* __restrict__ qkv) {
  int srow = BLKR + blockIdx.x;
  int t = threadIdx.x;
  __shared__ float hsl[Dm];
  __shared__ float tl[32];
  for (int e = t; e < Dm; e += 256) hsl[e] = hs[(size_t)srow * Dm + e];
  __syncthreads();
  int dot = t >> 3, part = t & 7;
  int mat = dot >> 4, j = dot & 15;
  const float* down = mat ? v_down : k_down;
  float p = 0.f;
  for (int e = part; e < Dm; e += 8) p += hsl[e] * down[j * Dm + e];
  p += __shfl_xor(p, 1, 64);
  p += __shfl_xor(p, 2, 64);
  p += __shfl_xor(p, 4, 64);
  if (part == 0) tl[dot] = p;
  __syncthreads();
  float tk[16], tv[16];
#pragma unroll
  for (int jj = 0; jj < 16; jj++) { tk[jj] = tl[jj]; tv[jj] = tl[16 + jj]; }
  for (int n = t; n < Dm; n += 256) {
    float ak = 0.f, av = 0.f;
#pragma unroll
    for (int jj = 0; jj < 16; jj++) {
      ak += tk[jj] * k_up[n * 16 + jj];
      av += tv[jj] * v_up[n * 16 + jj];
    }
    qkv[(size_t)srow * NDm + 3072 + n] += ak;
    qkv[(size_t)srow * NDm + 6144 + n] += av;
  }
}

// ---------------- RMSNorm + RoPE -> bf16 head-major q,k ----------------
__global__ __launch_bounds__(256) void prep_kernel(
    const float* __restrict__ qkv,
    const float* __restrict__ nqw, const float* __restrict__ nkw,
    const float* __restrict__ rc, const float* __restrict__ rs,
    unsigned short* __restrict__ qh, unsigned short* __restrict__ kh) {
  int s = blockIdx.x;
  int w = threadIdx.x >> 6, l = threadIdx.x & 63;
  int d0 = l * 2;
  float c0 = rc[s * 128 + d0], c1 = rc[s * 128 + d0 + 1];
  float s0 = rs[s * 128 + d0], s1 = rs[s * 128 + d0 + 1];
  float wk0 = nkw[d0], wk1 = nkw[d0 + 1];
  float wq0 = nqw[d0], wq1 = nqw[d0 + 1];
  bool doq = (s < BLKR);

#pragma unroll
  for (int hh = 0; hh < 6; hh++) {
    int h = w * 6 + hh;
    { // k: all rows
      const float* kp = qkv + (size_t)s * NDm + 3072 + h * 128;
      float2 x = *(const float2*)(kp + d0);
      float ss = x.x * x.x + x.y * x.y;
#pragma unroll
      for (int m = 1; m < 64; m <<= 1) ss += __shfl_xor(ss, m, 64);
      float r = rsqrtf(ss * (1.f / 128.f) + 1e-6f);
      float xn0 = x.x * r * wk0, xn1 = x.y * r * wk1;
      ushort2 o = make_ushort2(f2bf(xn0 * c0 - xn1 * s0), f2bf(xn1 * c1 + xn0 * s1));
      *(ushort2*)&kh[((size_t)h * Sq + s) * 128 + d0] = o;
    }
    if (doq) { // q: only output rows
      const float* qp = qkv + (size_t)s * NDm + h * 128;
      float2 x = *(const float2*)(qp + d0);
      float ss = x.x * x.x + x.y * x.y;
#pragma unroll
      for (int m = 1; m < 64; m <<= 1) ss += __shfl_xor(ss, m, 64);
      float r = rsqrtf(ss * (1.f / 128.f) + 1e-6f);
      float xn0 = x.x * r * wq0, xn1 = x.y * r * wq1;
      ushort2 o = make_ushort2(f2bf(xn0 * c0 - xn1 * s0), f2bf(xn1 * c1 + xn0 * s1));
      *(ushort2*)&qh[((size_t)h * BLKR + s) * 128 + d0] = o;
    }
  }
}

// ---------------- v transpose to V^T per head (bf16) ----------------
__global__ __launch_bounds__(256) void vt_kernel(const float* __restrict__ qkv,
                                                 unsigned short* __restrict__ vt) {
  int st = blockIdx.x, dt = blockIdx.y, h = blockIdx.z;
  int tx = threadIdx.x & 31, ty = threadIdx.x >> 5;
  __shared__ float ld[32][33];
  int s0 = st * 32, d0 = dt * 32;
#pragma unroll
  for (int p = 0; p < 4; p++) {
    int ss = ty + p * 8;
    ld[ss][tx] = qkv[(size_t)(s0 + ss) * NDm + 6144 + h * 128 + d0 + tx];
  }
  __syncthreads();
#pragma unroll
  for (int p = 0; p < 4; p++) {
    int dd = ty + p * 8;
    vt[((size_t)h * 128 + d0 + dd) * Sq + s0 + tx] = f2bf(ld[tx][dd]);
  }
}

// ------- flash attention: SWAPPED QK^T, in-register P exchange (fixed) -----
// S^T = mfma(K_frag, Q_frag): lane (lr,lg) holds S[key=kb*16+lg*4+i][qrow=lr].
// PV B-frag built via 8x ds_bpermute + 4x select (pull semantics: the kb
// choice must be made in the DESTINATION lane, after the gather — r11 bug).
__global__ __launch_bounds__(256) void attn_kernel(
    const unsigned short* __restrict__ qh,  // [NH][1152][128]
    const unsigned short* __restrict__ kh,  // [NH][2176][128]
    const unsigned short* __restrict__ vt,  // [NH][128][2176]
    float* __restrict__ accW,               // [2][1152][3072] partial acc
    float* __restrict__ lW) {               // [2][24][1152] partial lsum
  int bid = blockIdx.x;
  int wg = (bid & 7) * 108 + (bid >> 3);    // bijective: 864 = 8 x 108
  int h = wg / 36, rem = wg % 36;
  int qt = rem >> 1, split = rem & 1;
  int q0 = qt * 64;
  int k0 = split * KVH;

  int t = threadIdx.x;
  int w = t >> 6, lane = t & 63;
  int lr = lane & 15, lg = lane >> 4;

  __shared__ __attribute__((aligned(16))) unsigned short kLds[2][32 * 128];
  __shared__ __attribute__((aligned(16))) unsigned short vLds[2][128 * 32];

  // Q fragments (B operand of swapped QK): Q[qrow=lr][d = m*32 + lg*8 + j]
  const unsigned short* qb = qh + ((size_t)h * BLKR + q0 + w * 16) * 128;
  bf16x8 aq[4];
#pragma unroll
  for (int m = 0; m < 4; m++)
    aq[m] = *(const bf16x8*)(qb + (size_t)lr * 128 + m * 32 + lg * 8);

  const unsigned short* kh_h = kh + ((size_t)h * Sq + k0) * 128;
  const unsigned short* vt_h = vt + (size_t)h * 128 * Sq + k0;

  // staging sources (pre-swizzled): K tile 32x128 (slot^row&7);
  // V^T tile 128x32 (slot^row&3). Linear LDS dest.
  const unsigned short* srcK[2];
  const unsigned short* srcV[2];
  int kDst[2], vDst[2];
#pragma unroll
  for (int c = 0; c < 2; c++) {
    int u = c * 256 + t;
    int rK = u >> 4, sK = u & 15;
    srcK[c] = kh_h + (size_t)rK * 128 + ((sK ^ (rK & 7)) * 8);
    kDst[c] = u * 8;
    int rV = u >> 2, sV = u & 3;
    srcV[c] = vt_h + (size_t)rV * Sq + ((sV ^ (rV & 3)) * 8);
    vDst[c] = u * 8;
  }

  auto stage = [&](int kt, int buf) {
#pragma unroll
    for (int c = 0; c < 2; c++)
      __builtin_amdgcn_global_load_lds(
          (const AS1 void*)(srcK[c] + (size_t)kt * 4096),
          (AS3 void*)(&kLds[buf][kDst[c]]), 16, 0, 0);
#pragma unroll
    for (int c = 0; c < 2; c++)
      __builtin_amdgcn_global_load_lds(
          (const AS1 void*)(srcV[c] + (size_t)kt * 32),
          (AS3 void*)(&vLds[buf][vDst[c]]), 16, 0, 0);
  };

  f32x4 acc[8];
#pragma unroll
  for (int o = 0; o < 8; o++) acc[o] = (f32x4){0.f, 0.f, 0.f, 0.f};
  float lsum = 0.f;
  const float sc = 0.08838834764831845f;   // 1/sqrt(128)
  const float L2E = 1.4426950408889634f;
  const float ea = sc * L2E, eb = -10.0f * L2E;   // fixed M = 10

  int lr7 = lr & 7, lr3 = lr & 3;
  // gather addresses: dword pairs come from lanes (lr, g0=2*(lg&1)) and g0+1
  int adLo = ((((lg & 1) << 1)) * 16 + lr) * 4;
  int adHi = adLo + 64;
  bool hiKb = (lg & 2) != 0;   // dest lanes lg>=2 need the kb=1 registers

  auto compute = [&](int buf) {
    const unsigned short* kbuf = kLds[buf];
    const unsigned short* vbuf = vLds[buf];
    f32x4 s2[2];
    s2[0] = (f32x4){0.f, 0.f, 0.f, 0.f};
    s2[1] = (f32x4){0.f, 0.f, 0.f, 0.f};
    __builtin_amdgcn_s_setprio(1);
#pragma unroll
    for (int kb = 0; kb < 2; kb++)
#pragma unroll
      for (int m = 0; m < 4; m++) {
        // A operand: K[key = kb*16+lr][d-chunk m] (swizzled)
        bf16x8 kf = *(const bf16x8*)&kbuf[(kb * 16 + lr) * 128 + ((m * 4 + lg) ^ lr7) * 8];
        s2[kb] = __builtin_amdgcn_mfma_f32_16x16x32_bf16(kf, aq[m], s2[kb], 0, 0, 0);
      }
    __builtin_amdgcn_s_setprio(0);
    // P = exp2(s*ea + eb); lane holds keys kb*16+lg*4+i of q-row lr
    unsigned pk0[2], pk1[2];   // [kb][pair]: pair0 = (i0,i1), pair1 = (i2,i3)
#pragma unroll
    for (int kb = 0; kb < 2; kb++) {
      float p0 = exp2f(fmaf(s2[kb][0], ea, eb));
      float p1 = exp2f(fmaf(s2[kb][1], ea, eb));
      float p2 = exp2f(fmaf(s2[kb][2], ea, eb));
      float p3 = exp2f(fmaf(s2[kb][3], ea, eb));
      lsum += (p0 + p1) + (p2 + p3);
      unsigned r0, r1;
      asm("v_cvt_pk_bf16_f32 %0, %1, %2" : "=v"(r0) : "v"(p0), "v"(p1));
      asm("v_cvt_pk_bf16_f32 %0, %1, %2" : "=v"(r1) : "v"(p2), "v"(p3));
      if (kb == 0) { pk0[0] = r0; pk0[1] = r1; }
      else         { pk1[0] = r0; pk1[1] = r1; }
    }
    // gather BOTH kb variants, select in the destination lane (bpermute pulls
    // the SOURCE lane's register; the source serves kb=0 and kb=1 consumers)
    int a00 = __builtin_amdgcn_ds_bpermute(adLo, (int)pk0[0]);
    int a01 = __builtin_amdgcn_ds_bpermute(adLo, (int)pk0[1]);
    int a10 = __builtin_amdgcn_ds_bpermute(adLo, (int)pk1[0]);
    int a11 = __builtin_amdgcn_ds_bpermute(adLo, (int)pk1[1]);
    int b00 = __builtin_amdgcn_ds_bpermute(adHi, (int)pk0[0]);
    int b01 = __builtin_amdgcn_ds_bpermute(adHi, (int)pk0[1]);
    int b10 = __builtin_amdgcn_ds_bpermute(adHi, (int)pk1[0]);
    int b11 = __builtin_amdgcn_ds_bpermute(adHi, (int)pk1[1]);
    int4 pw;
    pw.x = hiKb ? a10 : a00;   // keys 8lg+0,1
    pw.y = hiKb ? a11 : a01;   // keys 8lg+2,3
    pw.z = hiKb ? b10 : b00;   // keys 8lg+4,5
    pw.w = hiKb ? b11 : b01;   // keys 8lg+6,7
    bf16x8 pfrag = __builtin_bit_cast(bf16x8, pw);
    __builtin_amdgcn_s_setprio(1);
#pragma unroll
    for (int o = 0; o < 8; o++) {
      // A operand: V^T[d = o*16+lr][keys] (swizzled)
      bf16x8 vf = *(const bf16x8*)&vbuf[(o * 16 + lr) * 32 + (lg ^ lr3) * 8];
      acc[o] = __builtin_amdgcn_mfma_f32_16x16x32_bf16(vf, pfrag, acc[o], 0, 0, 0);
    }
    __builtin_amdgcn_s_setprio(0);
  };

  stage(0, 0);
  __syncthreads();
  for (int kt = 0; kt < NT2; kt += 2) {
    stage(kt + 1, 1);
    compute(0);
    __syncthreads();
    if (kt + 2 < NT2) stage(kt + 2, 0);
    compute(1);
    __syncthreads();
  }

  // row-sum: lanes (lr, lg=0..3) each hold a disjoint 8-key partial of row lr
  lsum += __shfl_xor(lsum, 16, 64);
  lsum += __shfl_xor(lsum, 32, 64);

  // acc[o][i] = O^T[d = o*16 + lg*4 + i][qrow = lr] -> float4 per o
  float* accP = accW + (size_t)split * BLKR * 3072;
  size_t rowOff = (size_t)(q0 + w * 16 + lr) * 3072 + h * 128;
#pragma unroll
  for (int o = 0; o < 8; o++)
    *(f32x4*)&accP[rowOff + o * 16 + lg * 4] = acc[o];
  if (lg == 0) {
    float* lP = lW + (size_t)split * NH * BLKR + (size_t)h * BLKR;
    lP[q0 + w * 16 + lr] = lsum;
  }
}

// ---------------- combine: out = (a0+a1)/(l0+l1) ----------------
__global__ __launch_bounds__(256) void normalize_kernel(
    const float* __restrict__ accW, const float* __restrict__ lW,
    float* __restrict__ out) {
  int idx = blockIdx.x * 256 + threadIdx.x;      // 442368 total
  int r = idx / 384, rem = idx % 384;
  int c = rem * 8, h = c >> 7;
  const float4* a0 = (const float4*)(accW + (size_t)r * 3072 + c);
  const float4* a1 = (const float4*)(accW + (size_t)BLKR * 3072 + (size_t)r * 3072 + c);
  float l = lW[(size_t)h * BLKR + r] + lW[(size_t)NH * BLKR + (size_t)h * BLKR + r];
  float inv = 1.0f / l;
  float4 v0 = a0[0], v1 = a0[1], u0 = a1[0], u1 = a1[1];
  float4 o0, o1;
  o0.x = (v0.x + u0.x) * inv; o0.y = (v0.y + u0.y) * inv;
  o0.z = (v0.z + u0.z) * inv; o0.w = (v0.w + u0.w) * inv;
  o1.x = (v1.x + u1.x) * inv; o1.y = (v1.y + u1.y) * inv;
  o1.z = (v1.z + u1.z) * inv; o1.w = (v1.w + u1.w) * inv;
  float4* op = (float4*)(out + (size_t)r * 3072 + c);
  op[0] = o0; op[1] = o1;
}

extern "C" void kernel_launch(void* const* d_in, const int* in_sizes, int n_in,
                              void* d_out, int out_size, void* d_ws, size_t ws_size,
                              hipStream_t stream) {
  const float* hs  = (const float*)d_in[0];
  const float* Wq  = (const float*)d_in[1];
  const float* bq  = (const float*)d_in[2];
  const float* Wk  = (const float*)d_in[3];
  const float* bk  = (const float*)d_in[4];
  const float* Wv  = (const float*)d_in[5];
  const float* bv  = (const float*)d_in[6];
  const float* k_down = (const float*)d_in[9];
  const float* k_up   = (const float*)d_in[10];
  const float* v_down = (const float*)d_in[11];
  const float* v_up   = (const float*)d_in[12];
  const float* nqw = (const float*)d_in[13];
  const float* nkw = (const float*)d_in[14];
  const float* rc  = (const float*)d_in[15];
  const float* rsn = (const float*)d_in[16];
  float* out = (float*)d_out;

  char* ws = (char*)d_ws;
  unsigned short* hsb = (unsigned short*)(ws + 0);          // 13,369,344 B
  unsigned short* wb  = (unsigned short*)(ws + 13369344);   // 56,623,104 B
  float*          qkv = (float*)(ws + 69992448);            // 80,216,064 B
  unsigned short* qh  = (unsigned short*)(ws + 150208512);  //  7,077,888 B
  unsigned short* kh  = (unsigned short*)(ws + 157286400);  // 13,369,344 B
  unsigned short* vtb = (unsigned short*)(ws + 170655744);  // 13,369,344 B
  // attn partials reuse the qkv region (dead after prep+vt):
  float* accW = qkv;                                        // 28,311,552 B
  float* lW   = (float*)(ws + 69992448 + 28311552);         //    221,184 B

  const int n8_hs = Sq * Dm / 8;
  const int n8_w  = Dm * Dm / 8;
  cvt_kernel<<<dim3((n8_hs + 255) / 256), 256, 0, stream>>>(hs, hsb, n8_hs);
  cvt3_kernel<<<dim3((n8_w + 255) / 256, 3), 256, 0, stream>>>(Wq, Wk, Wv, wb, n8_w);

  gemm_kernel<<<dim3(1032), 256, 0, stream>>>(hsb, wb, bq, bk, bv, qkv);
  lora_kernel<<<dim3(Sq - BLKR), 256, 0, stream>>>(hs, k_down, k_up, v_down, v_up, qkv);
  prep_kernel<<<dim3(Sq), 256, 0, stream>>>(qkv, nqw, nkw, rc, rsn, qh, kh);
  vt_kernel<<<dim3(Sq / 32, HDm / 32, NH), 256, 0, stream>>>(qkv, vtb);
  attn_kernel<<<dim3(2 * 18 * NH), 256, 0, stream>>>(qh, kh, vtb, accW, lW);
  normalize_kernel<<<dim3(BLKR * 3072 / 8 / 256), 256, 0, stream>>>(accW, lW, out);
}

// Round 13
// 304.012 us; speedup vs baseline: 1.2247x; 1.1945x over previous
//
#include <hip/hip_runtime.h>
#include <stdint.h>

#define Sq   2176
#define Dm   3072
#define NDm  9216
#define NH   24
#define HDm  128
#define BLKR 1152   // S - COND
#define KVH  1088   // KV half-range per split
#define NT2  34     // 32-key tiles per split

typedef __attribute__((ext_vector_type(8))) __bf16 bf16x8;
typedef __attribute__((ext_vector_type(4))) float f32x4;
typedef __attribute__((ext_vector_type(8))) unsigned short ushort8;

#define AS1 __attribute__((address_space(1)))
#define AS3 __attribute__((address_space(3)))

__device__ __forceinline__ unsigned short f2bf(float x) {
  unsigned u = __builtin_bit_cast(unsigned, x);
  u += 0x7FFFu + ((u >> 16) & 1u);   // RNE; inputs are finite randoms
  return (unsigned short)(u >> 16);
}

// ---------------- f32 -> bf16 conversion, 8 elems/thread ----------------
__global__ void cvt_kernel(const float* __restrict__ src,
                           unsigned short* __restrict__ dst, int n8) {
  int i = blockIdx.x * blockDim.x + threadIdx.x;
  if (i >= n8) return;
  const float4* s4 = (const float4*)src + (size_t)i * 2;
  float4 a = s4[0], b = s4[1];
  ushort8 o;
  o[0]=f2bf(a.x); o[1]=f2bf(a.y); o[2]=f2bf(a.z); o[3]=f2bf(a.w);
  o[4]=f2bf(b.x); o[5]=f2bf(b.y); o[6]=f2bf(b.z); o[7]=f2bf(b.w);
  *((ushort8*)dst + i) = o;
}

// 3 weight matrices in one launch (blockIdx.y selects source)
__global__ void cvt3_kernel(const float* __restrict__ w0, const float* __restrict__ w1,
                            const float* __restrict__ w2,
                            unsigned short* __restrict__ dst, int n8) {
  int i = blockIdx.x * blockDim.x + threadIdx.x;
  if (i >= n8) return;
  const float* src = blockIdx.y == 0 ? w0 : (blockIdx.y == 1 ? w1 : w2);
  const float4* s4 = (const float4*)src + (size_t)i * 2;
  float4 a = s4[0], b = s4[1];
  ushort8 o;
  o[0]=f2bf(a.x); o[1]=f2bf(a.y); o[2]=f2bf(a.z); o[3]=f2bf(a.w);
  o[4]=f2bf(b.x); o[5]=f2bf(b.y); o[6]=f2bf(b.z); o[7]=f2bf(b.w);
  *((ushort8*)dst + (size_t)blockIdx.y * (Dm * (size_t)Dm / 8) + i) = o;
}

// ---------------- LoRA down-projection: T = hm @ down^T (rows >= 1152) ----
__global__ __launch_bounds__(256) void lorat_kernel(
    const float* __restrict__ hs,
    const float* __restrict__ k_down, const float* __restrict__ v_down,
    float* __restrict__ tkW, float* __restrict__ tvW) {
  int srow = BLKR + blockIdx.x;
  int t = threadIdx.x;
  __shared__ float hsl[Dm];
  __shared__ float tl[32];
  for (int e = t; e < Dm; e += 256) hsl[e] = hs[(size_t)srow * Dm + e];
  __syncthreads();
  int dot = t >> 3, part = t & 7;
  int mat = dot >> 4, j = dot & 15;
  const float* down = mat ? v_down : k_down;
  float p = 0.f;
  for (int e = part; e < Dm; e += 8) p += hsl[e] * down[j * Dm + e];
  p += __shfl_xor(p, 1, 64);
  p += __shfl_xor(p, 2, 64);
  p += __shfl_xor(p, 4, 64);
  if (part == 0) tl[dot] = p;
  __syncthreads();
  if (t < 16) tkW[(size_t)blockIdx.x * 16 + t] = tl[t];
  else if (t < 32) tvW[(size_t)blockIdx.x * 16 + (t - 16)] = tl[t];
}

// ------- fused QKV GEMM + bias + LoRA + RMSNorm + RoPE + V-transpose ------
// Main loop = round-8 proven structure (770 TF). Epilogue is tile-local:
// each tile is (128 rows x one full head). LoRA applied as ONE extra
// swizzled MFMA half-pass (T,U staged bf16 into aL/bL, j 16..31 zeroed).
__global__ __launch_bounds__(256, 4) void gemm_kernel(
    const unsigned short* __restrict__ A,
    const unsigned short* __restrict__ B,
    const float* __restrict__ bq, const float* __restrict__ bk,
    const float* __restrict__ bv,
    const float* __restrict__ tkW, const float* __restrict__ tvW,
    const float* __restrict__ kup, const float* __restrict__ vup,
    const float* __restrict__ nqw, const float* __restrict__ nkw,
    const float* __restrict__ rc, const float* __restrict__ rs,
    unsigned short* __restrict__ qh, unsigned short* __restrict__ kh,
    unsigned short* __restrict__ vtb) {
  __shared__ __attribute__((aligned(16))) unsigned short sm[17408]; // 34.8KB
  __shared__ float rsum[2][2][64];
  int t = threadIdx.x;
  int wid = t >> 6, lane = t & 63;
  int lr = lane & 15, lg = lane >> 4;
  int wr = wid >> 1, wc = wid & 1;

  int bid = blockIdx.x;
  int wg = (bid & 7) * 129 + (bid >> 3);
  int mt, nt;
  if (wg < 216) { nt = wg / 9; mt = wg % 9; }
  else { int r2 = wg - 216; nt = 24 + r2 / 17; mt = r2 % 17; }
  int m0 = mt * 128, n0 = nt * 128;

  f32x4 acc[4][4];
#pragma unroll
  for (int m = 0; m < 4; m++)
#pragma unroll
    for (int n = 0; n < 4; n++) acc[m][n] = (f32x4){0.f, 0.f, 0.f, 0.f};

  int tr = t >> 3;
  int uu = (t & 7) ^ (tr & 7);
  const unsigned short* pA = A + (size_t)(m0 + tr) * Dm + uu * 8;
  const unsigned short* pB = B + (size_t)(n0 + tr) * Dm + uu * 8;

  int lr7 = lr & 7;
  int baseA = (wr * 64 + lr) * 64;
  int baseB = (wc * 64 + lr) * 64;
  int d0 = (lg ^ lr7) * 8;
  int d1 = ((4 + lg) ^ lr7) * 8;

  for (int kt = 0; kt < Dm / 64; kt++) {
    const int ko = kt * 64;
#pragma unroll
    for (int c = 0; c < 4; c++) {
      __builtin_amdgcn_global_load_lds(
          (const AS1 void*)(pA + (size_t)c * 32 * Dm + ko),
          (AS3 void*)(&sm[c * 2048 + wid * 512]), 16, 0, 0);
      __builtin_amdgcn_global_load_lds(
          (const AS1 void*)(pB + (size_t)c * 32 * Dm + ko),
          (AS3 void*)(&sm[8192 + c * 2048 + wid * 512]), 16, 0, 0);
    }
    __syncthreads();

    bf16x8 a0[4], b0[4];
#pragma unroll
    for (int m = 0; m < 4; m++) a0[m] = *(const bf16x8*)&sm[baseA + m * 1024 + d0];
#pragma unroll
    for (int n = 0; n < 4; n++) b0[n] = *(const bf16x8*)&sm[8192 + baseB + n * 1024 + d0];
#pragma unroll
    for (int m = 0; m < 4; m++)
#pragma unroll
      for (int n = 0; n < 4; n++)
        acc[m][n] = __builtin_amdgcn_mfma_f32_16x16x32_bf16(a0[m], b0[n], acc[m][n], 0, 0, 0);

    bf16x8 a1[4], b1[4];
#pragma unroll
    for (int m = 0; m < 4; m++) a1[m] = *(const bf16x8*)&sm[baseA + m * 1024 + d1];
#pragma unroll
    for (int n = 0; n < 4; n++) b1[n] = *(const bf16x8*)&sm[8192 + baseB + n * 1024 + d1];
#pragma unroll
    for (int m = 0; m < 4; m++)
#pragma unroll
      for (int n = 0; n < 4; n++)
        acc[m][n] = __builtin_amdgcn_mfma_f32_16x16x32_bf16(a1[m], b1[n], acc[m][n], 0, 0, 0);
    __syncthreads();
  }

  // ---- fused epilogue ----
  int region = nt < 24 ? 0 : (nt < 48 ? 1 : 2);
  int h = region == 0 ? nt : (region == 1 ? nt - 24 : nt - 48);
  int dcol[4];
#pragma unroll
  for (int n = 0; n < 4; n++) dcol[n] = wc * 64 + n * 16 + lr;
  const float* bias = region == 0 ? bq : (region == 1 ? bk : bv);
#pragma unroll
  for (int n = 0; n < 4; n++) {
    float b = bias[h * 128 + dcol[n]];
#pragma unroll
    for (int m = 0; m < 4; m++)
#pragma unroll
      for (int i = 0; i < 4; i++) acc[m][n][i] += b;
  }

  if (region >= 1 && m0 >= BLKR) {
    // LoRA rank-16 update: stage T (A) and U (B) bf16 into the main-loop
    // swizzled layout; logical k 16..31 zeroed; one 8-MFMA half-pass.
    const float* tW = region == 1 ? tkW : tvW;
    const float* up = region == 1 ? kup : vup;
    int rr = t >> 1, half = t & 1;
    const float* srcT = tW + ((size_t)(m0 - BLKR) + rr) * 16 + half * 8;
    const float* srcU = up + ((size_t)h * 128 + rr) * 16 + half * 8;
    ushort8 vT, vU;
#pragma unroll
    for (int u2 = 0; u2 < 8; u2++) { vT[u2] = f2bf(srcT[u2]); vU[u2] = f2bf(srcU[u2]); }
    ushort8 z = {0, 0, 0, 0, 0, 0, 0, 0};
    *(ushort8*)&sm[(rr * 8 + (half ^ (rr & 7))) * 8] = vT;
    *(ushort8*)&sm[(rr * 8 + ((2 + half) ^ (rr & 7))) * 8] = z;
    *(ushort8*)&sm[8192 + (rr * 8 + (half ^ (rr & 7))) * 8] = vU;
    *(ushort8*)&sm[8192 + (rr * 8 + ((2 + half) ^ (rr & 7))) * 8] = z;
    __syncthreads();
    bf16x8 a0[4], b0[4];
#pragma unroll
    for (int m = 0; m < 4; m++) a0[m] = *(const bf16x8*)&sm[baseA + m * 1024 + d0];
#pragma unroll
    for (int n = 0; n < 4; n++) b0[n] = *(const bf16x8*)&sm[8192 + baseB + n * 1024 + d0];
#pragma unroll
    for (int m = 0; m < 4; m++)
#pragma unroll
      for (int n = 0; n < 4; n++)
        acc[m][n] = __builtin_amdgcn_mfma_f32_16x16x32_bf16(a0[m], b0[n], acc[m][n], 0, 0, 0);
    __syncthreads();
  }

  if (region <= 1) {
    // RMSNorm row sums (cols of a row live in 16 lr lanes x 2 wc waves)
    float part[4][4];
#pragma unroll
    for (int m = 0; m < 4; m++)
#pragma unroll
      for (int i = 0; i < 4; i++) {
        float p = acc[m][0][i] * acc[m][0][i] + acc[m][1][i] * acc[m][1][i]
                + acc[m][2][i] * acc[m][2][i] + acc[m][3][i] * acc[m][3][i];
#pragma unroll
        for (int d = 1; d < 16; d <<= 1) p += __shfl_xor(p, d, 64);
        part[m][i] = p;
      }
    if (lr == 0) {
#pragma unroll
      for (int m = 0; m < 4; m++)
#pragma unroll
        for (int i = 0; i < 4; i++) rsum[wr][wc][m * 16 + lg * 4 + i] = part[m][i];
    }
    __syncthreads();
    const float* nw = region == 0 ? nqw : nkw;
    float wv[4];
#pragma unroll
    for (int n = 0; n < 4; n++) wv[n] = nw[dcol[n]];
    unsigned short* dstb = region == 0 ? qh : kh;
    int srows = region == 0 ? BLKR : Sq;
#pragma unroll
    for (int m = 0; m < 4; m++)
#pragma unroll
      for (int i = 0; i < 4; i++) {
        int idx = m * 16 + lg * 4 + i;
        float s2 = rsum[wr][0][idx] + rsum[wr][1][idx];
        float rinv = rsqrtf(s2 * (1.f / 128.f) + 1e-6f);
        int r = m0 + wr * 64 + idx;
#pragma unroll
        for (int n = 0; n < 4; n++) {
          float xn = acc[m][n][i] * rinv * wv[n];
          float xp = __shfl_xor(xn, 1, 64);      // partner col (lr^1), same row
          float c = rc[r * 128 + dcol[n]];
          float s = rs[r * 128 + dcol[n]];
          float rot = (dcol[n] & 1) ? xp : -xp;
          dstb[((size_t)h * srows + r) * 128 + dcol[n]] = f2bf(xn * c + rot * s);
        }
      }
  } else {
    // V: in-LDS 128x128 transpose (stride 136 = 16B-aligned rows) -> V^T
#pragma unroll
    for (int m = 0; m < 4; m++)
#pragma unroll
      for (int i = 0; i < 4; i++) {
        int rl = wr * 64 + m * 16 + lg * 4 + i;
#pragma unroll
        for (int n = 0; n < 4; n++)
          sm[dcol[n] * 136 + rl] = f2bf(acc[m][n][i]);
      }
    __syncthreads();
    int d = t >> 1, rc0 = (t & 1) * 64;
    unsigned short* dv = vtb + ((size_t)h * 128 + d) * Sq + m0 + rc0;
#pragma unroll
    for (int u = 0; u < 8; u++)
      *(ushort8*)(dv + u * 8) = *(const ushort8*)&sm[d * 136 + rc0 + u * 8];
  }
}

// ------- flash attention: SWAPPED QK^T, in-register P exchange (r12) -------
__global__ __launch_bounds__(256) void attn_kernel(
    const unsigned short* __restrict__ qh,  // [NH][1152][128]
    const unsigned short* __restrict__ kh,  // [NH][2176][128]
    const unsigned short* __restrict__ vt,  // [NH][128][2176]
    float* __restrict__ accW,               // [2][1152][3072] partial acc
    float* __restrict__ lW) {               // [2][24][1152] partial lsum
  int bid = blockIdx.x;
  int wg = (bid & 7) * 108 + (bid >> 3);    // bijective: 864 = 8 x 108
  int h = wg / 36, rem = wg % 36;
  int qt = rem >> 1, split = rem & 1;
  int q0 = qt * 64;
  int k0 = split * KVH;

  int t = threadIdx.x;
  int w = t >> 6, lane = t & 63;
  int lr = lane & 15, lg = lane >> 4;

  __shared__ __attribute__((aligned(16))) unsigned short kLds[2][32 * 128];
  __shared__ __attribute__((aligned(16))) unsigned short vLds[2][128 * 32];

  const unsigned short* qb = qh + ((size_t)h * BLKR + q0 + w * 16) * 128;
  bf16x8 aq[4];
#pragma unroll
  for (int m = 0; m < 4; m++)
    aq[m] = *(const bf16x8*)(qb + (size_t)lr * 128 + m * 32 + lg * 8);

  const unsigned short* kh_h = kh + ((size_t)h * Sq + k0) * 128;
  const unsigned short* vt_h = vt + (size_t)h * 128 * Sq + k0;

  const unsigned short* srcK[2];
  const unsigned short* srcV[2];
  int kDst[2], vDst[2];
#pragma unroll
  for (int c = 0; c < 2; c++) {
    int u = c * 256 + t;
    int rK = u >> 4, sK = u & 15;
    srcK[c] = kh_h + (size_t)rK * 128 + ((sK ^ (rK & 7)) * 8);
    kDst[c] = u * 8;
    int rV = u >> 2, sV = u & 3;
    srcV[c] = vt_h + (size_t)rV * Sq + ((sV ^ (rV & 3)) * 8);
    vDst[c] = u * 8;
  }

  auto stage = [&](int kt, int buf) {
#pragma unroll
    for (int c = 0; c < 2; c++)
      __builtin_amdgcn_global_load_lds(
          (const AS1 void*)(srcK[c] + (size_t)kt * 4096),
          (AS3 void*)(&kLds[buf][kDst[c]]), 16, 0, 0);
#pragma unroll
    for (int c = 0; c < 2; c++)
      __builtin_amdgcn_global_load_lds(
          (const AS1 void*)(srcV[c] + (size_t)kt * 32),
          (AS3 void*)(&vLds[buf][vDst[c]]), 16, 0, 0);
  };

  f32x4 acc[8];
#pragma unroll
  for (int o = 0; o < 8; o++) acc[o] = (f32x4){0.f, 0.f, 0.f, 0.f};
  float lsum = 0.f;
  const float sc = 0.08838834764831845f;   // 1/sqrt(128)
  const float L2E = 1.4426950408889634f;
  const float ea = sc * L2E, eb = -10.0f * L2E;   // fixed M = 10

  int lr7 = lr & 7, lr3 = lr & 3;
  int adLo = ((((lg & 1) << 1)) * 16 + lr) * 4;
  int adHi = adLo + 64;
  bool hiKb = (lg & 2) != 0;

  auto compute = [&](int buf) {
    const unsigned short* kbuf = kLds[buf];
    const unsigned short* vbuf = vLds[buf];
    f32x4 s2[2];
    s2[0] = (f32x4){0.f, 0.f, 0.f, 0.f};
    s2[1] = (f32x4){0.f, 0.f, 0.f, 0.f};
    __builtin_amdgcn_s_setprio(1);
#pragma unroll
    for (int kb = 0; kb < 2; kb++)
#pragma unroll
      for (int m = 0; m < 4; m++) {
        bf16x8 kf = *(const bf16x8*)&kbuf[(kb * 16 + lr) * 128 + ((m * 4 + lg) ^ lr7) * 8];
        s2[kb] = __builtin_amdgcn_mfma_f32_16x16x32_bf16(kf, aq[m], s2[kb], 0, 0, 0);
      }
    __builtin_amdgcn_s_setprio(0);
    unsigned pk0[2], pk1[2];
#pragma unroll
    for (int kb = 0; kb < 2; kb++) {
      float p0 = exp2f(fmaf(s2[kb][0], ea, eb));
      float p1 = exp2f(fmaf(s2[kb][1], ea, eb));
      float p2 = exp2f(fmaf(s2[kb][2], ea, eb));
      float p3 = exp2f(fmaf(s2[kb][3], ea, eb));
      lsum += (p0 + p1) + (p2 + p3);
      unsigned r0, r1;
      asm("v_cvt_pk_bf16_f32 %0, %1, %2" : "=v"(r0) : "v"(p0), "v"(p1));
      asm("v_cvt_pk_bf16_f32 %0, %1, %2" : "=v"(r1) : "v"(p2), "v"(p3));
      if (kb == 0) { pk0[0] = r0; pk0[1] = r1; }
      else         { pk1[0] = r0; pk1[1] = r1; }
    }
    int a00 = __builtin_amdgcn_ds_bpermute(adLo, (int)pk0[0]);
    int a01 = __builtin_amdgcn_ds_bpermute(adLo, (int)pk0[1]);
    int a10 = __builtin_amdgcn_ds_bpermute(adLo, (int)pk1[0]);
    int a11 = __builtin_amdgcn_ds_bpermute(adLo, (int)pk1[1]);
    int b00 = __builtin_amdgcn_ds_bpermute(adHi, (int)pk0[0]);
    int b01 = __builtin_amdgcn_ds_bpermute(adHi, (int)pk0[1]);
    int b10 = __builtin_amdgcn_ds_bpermute(adHi, (int)pk1[0]);
    int b11 = __builtin_amdgcn_ds_bpermute(adHi, (int)pk1[1]);
    int4 pw;
    pw.x = hiKb ? a10 : a00;
    pw.y = hiKb ? a11 : a01;
    pw.z = hiKb ? b10 : b00;
    pw.w = hiKb ? b11 : b01;
    bf16x8 pfrag = __builtin_bit_cast(bf16x8, pw);
    __builtin_amdgcn_s_setprio(1);
#pragma unroll
    for (int o = 0; o < 8; o++) {
      bf16x8 vf = *(const bf16x8*)&vbuf[(o * 16 + lr) * 32 + (lg ^ lr3) * 8];
      acc[o] = __builtin_amdgcn_mfma_f32_16x16x32_bf16(vf, pfrag, acc[o], 0, 0, 0);
    }
    __builtin_amdgcn_s_setprio(0);
  };

  stage(0, 0);
  __syncthreads();
  for (int kt = 0; kt < NT2; kt += 2) {
    stage(kt + 1, 1);
    compute(0);
    __syncthreads();
    if (kt + 2 < NT2) stage(kt + 2, 0);
    compute(1);
    __syncthreads();
  }

  lsum += __shfl_xor(lsum, 16, 64);
  lsum += __shfl_xor(lsum, 32, 64);

  float* accP = accW + (size_t)split * BLKR * 3072;
  size_t rowOff = (size_t)(q0 + w * 16 + lr) * 3072 + h * 128;
#pragma unroll
  for (int o = 0; o < 8; o++)
    *(f32x4*)&accP[rowOff + o * 16 + lg * 4] = acc[o];
  if (lg == 0) {
    float* lP = lW + (size_t)split * NH * BLKR + (size_t)h * BLKR;
    lP[q0 + w * 16 + lr] = lsum;
  }
}

// ---------------- combine: out = (a0+a1)/(l0+l1) ----------------
__global__ __launch_bounds__(256) void normalize_kernel(
    const float* __restrict__ accW, const float* __restrict__ lW,
    float* __restrict__ out) {
  int idx = blockIdx.x * 256 + threadIdx.x;      // 442368 total
  int r = idx / 384, rem = idx % 384;
  int c = rem * 8, h = c >> 7;
  const float4* a0 = (const float4*)(accW + (size_t)r * 3072 + c);
  const float4* a1 = (const float4*)(accW + (size_t)BLKR * 3072 + (size_t)r * 3072 + c);
  float l = lW[(size_t)h * BLKR + r] + lW[(size_t)NH * BLKR + (size_t)h * BLKR + r];
  float inv = 1.0f / l;
  float4 v0 = a0[0], v1 = a0[1], u0 = a1[0], u1 = a1[1];
  float4 o0, o1;
  o0.x = (v0.x + u0.x) * inv; o0.y = (v0.y + u0.y) * inv;
  o0.z = (v0.z + u0.z) * inv; o0.w = (v0.w + u0.w) * inv;
  o1.x = (v1.x + u1.x) * inv; o1.y = (v1.y + u1.y) * inv;
  o1.z = (v1.z + u1.z) * inv; o1.w = (v1.w + u1.w) * inv;
  float4* op = (float4*)(out + (size_t)r * 3072 + c);
  op[0] = o0; op[1] = o1;
}

extern "C" void kernel_launch(void* const* d_in, const int* in_sizes, int n_in,
                              void* d_out, int out_size, void* d_ws, size_t ws_size,
                              hipStream_t stream) {
  const float* hs  = (const float*)d_in[0];
  const float* Wq  = (const float*)d_in[1];
  const float* bq  = (const float*)d_in[2];
  const float* Wk  = (const float*)d_in[3];
  const float* bk  = (const float*)d_in[4];
  const float* Wv  = (const float*)d_in[5];
  const float* bv  = (const float*)d_in[6];
  const float* k_down = (const float*)d_in[9];
  const float* k_up   = (const float*)d_in[10];
  const float* v_down = (const float*)d_in[11];
  const float* v_up   = (const float*)d_in[12];
  const float* nqw = (const float*)d_in[13];
  const float* nkw = (const float*)d_in[14];
  const float* rc  = (const float*)d_in[15];
  const float* rsn = (const float*)d_in[16];
  float* out = (float*)d_out;

  char* ws = (char*)d_ws;
  unsigned short* hsb = (unsigned short*)(ws + 0);          // 13,369,344 B
  unsigned short* wb  = (unsigned short*)(ws + 13369344);   // 56,623,104 B
  float* accW = (float*)(ws + 69992448);                    // 28,311,552 B
  float* lW   = (float*)(ws + 98304000);                    //    221,184 B
  float* tkW  = (float*)(ws + 98525184);                    //     65,536 B
  float* tvW  = (float*)(ws + 98590720);                    //     65,536 B
  unsigned short* qh  = (unsigned short*)(ws + 150208512);  //  7,077,888 B
  unsigned short* kh  = (unsigned short*)(ws + 157286400);  // 13,369,344 B
  unsigned short* vtb = (unsigned short*)(ws + 170655744);  // 13,369,344 B

  const int n8_hs = Sq * Dm / 8;
  const int n8_w  = Dm * Dm / 8;
  cvt_kernel<<<dim3((n8_hs + 255) / 256), 256, 0, stream>>>(hs, hsb, n8_hs);
  cvt3_kernel<<<dim3((n8_w + 255) / 256, 3), 256, 0, stream>>>(Wq, Wk, Wv, wb, n8_w);
  lorat_kernel<<<dim3(Sq - BLKR), 256, 0, stream>>>(hs, k_down, v_down, tkW, tvW);

  gemm_kernel<<<dim3(1032), 256, 0, stream>>>(hsb, wb, bq, bk, bv,
                                              tkW, tvW, k_up, v_up,
                                              nqw, nkw, rc, rsn, qh, kh, vtb);
  attn_kernel<<<dim3(2 * 18 * NH), 256, 0, stream>>>(qh, kh, vtb, accW, lW);
  normalize_kernel<<<dim3(BLKR * 3072 / 8 / 256), 256, 0, stream>>>(accW, lW, out);
}